// Round 1
// baseline (214.151 us; speedup 1.0000x reference)
//
#include <hip/hip_runtime.h>
#include <hip/hip_bf16.h>

// out[b, i*E + j] = x[b, i] * W[i, j]
// B=8192, L=100, E=64  -> out has 8192*6400 fp32 elements (209.7 MB)
// Memory-bound, write-dominated. One thread per float4 of output.
//
// Flat vec4 index v in [0, B*1600):
//   b  = v / 1600          (row of x / out)
//   r  = v % 1600          (vec4 offset within the row)
//   i  = r >> 4            (L index, since E/4 = 16 vec4 per i)
//   jv = r & 15
// W vec4 index = i*16 + jv = r  -> consecutive threads read consecutive W
// vec4s (coalesced, fully L1/L2 resident at 25.6 KB). 16 consecutive
// threads share one x[b*100+i] scalar (L1 broadcast).

#define LENGTH 100
#define EMBED 64
#define BATCH 8192
#define VEC4_PER_ROW (LENGTH * EMBED / 4)   // 1600

__global__ __launch_bounds__(256) void chemical_embedding_kernel(
    const float* __restrict__ x,
    const float* __restrict__ W,
    float4* __restrict__ out)
{
    int v = blockIdx.x * blockDim.x + threadIdx.x;   // < 13,107,200 fits int
    int b = v / VEC4_PER_ROW;
    int r = v - b * VEC4_PER_ROW;
    int i = r >> 4;

    float xs = x[b * LENGTH + i];
    float4 w = reinterpret_cast<const float4*>(W)[r];

    float4 o;
    o.x = xs * w.x;
    o.y = xs * w.y;
    o.z = xs * w.z;
    o.w = xs * w.w;
    out[v] = o;
}

extern "C" void kernel_launch(void* const* d_in, const int* in_sizes, int n_in,
                              void* d_out, int out_size, void* d_ws, size_t ws_size,
                              hipStream_t stream) {
    const float* x = (const float*)d_in[0];
    const float* W = (const float*)d_in[1];
    float4* out = (float4*)d_out;

    const int total_vec4 = BATCH * VEC4_PER_ROW;       // 13,107,200
    const int block = 256;
    const int grid = total_vec4 / block;               // 51,200 (divides exactly)

    chemical_embedding_kernel<<<grid, block, 0, stream>>>(x, W, out);
}